// Round 4
// baseline (54.849 us; speedup 1.0000x reference)
//
#include <hip/hip_runtime.h>
#include <hip/hip_bf16.h>

#define Bq 2
#define Sq 2048
#define Hq 16
#define CHUNK 64
#define NC 32

typedef __attribute__((ext_vector_type(8))) short short8;  // 8 bf16
typedef __attribute__((ext_vector_type(4))) float f32x4;
typedef unsigned short ushort_t;
typedef unsigned int uint_t;

__device__ inline short f2b(float f) {
  __hip_bfloat16 h = __float2bfloat16(f);
  return *reinterpret_cast<short*>(&h);
}

// XOR-swizzled element index for a 64x64 bf16 tile (128B rows, 16B slots).
__device__ inline int swz(int row, int col) {
  return (row << 6) + ((((col >> 3) ^ (row & 7))) << 3) + (col & 7);
}

// ---------------------------------------------------------------------------
// Kernel A: per-chunk KV sums -> wsM (linear [dv][dk] bf16), and V^T bf16
// tile (swizzled image) -> wsV for kernel C's direct fragment reads.
// ---------------------------------------------------------------------------
__global__ __launch_bounds__(256) void kv_chunk_kernel(
    const float* __restrict__ qk, const float* __restrict__ v,
    ushort_t* __restrict__ wsM, ushort_t* __restrict__ wsV) {
  const int u = blockIdx.x;
  const int c = u & 31, h = (u >> 5) & 15, b = u >> 9;
  const int t0 = c * CHUNK;
  const int tid = threadIdx.x;
  __shared__ short ktS[4096];   // K^T[dk][s], swizzled
  __shared__ short vtS[4096];   // V^T[dv][s], swizzled

  const int x = tid & 63, seg = tid >> 6;
  for (int e = 0; e < 2; ++e) {
    const int s0 = seg * 16 + e * 8;
    short8 kb, vb;
#pragma unroll
    for (int j = 0; j < 8; ++j) {
      const size_t t = (size_t)(b * Sq + t0 + s0 + j);
      kb[j] = f2b(qk[((t * 2 + 1) * Hq + h) * 64 + x]);   // coalesced column read
      vb[j] = f2b(v[(t * Hq + h) * 64 + x]);
    }
    *(short8*)&ktS[swz(x, s0)] = kb;
    *(short8*)&vtS[swz(x, s0)] = vb;
  }
  __syncthreads();

  const int w = tid >> 6, lane = tid & 63, g = lane >> 4, r16 = lane & 15;
  short8 vf[2];
#pragma unroll
  for (int kk = 0; kk < 2; ++kk)
    vf[kk] = *(const short8*)&vtS[swz(16 * w + r16, kk * 32 + 8 * g)];

  // Dump the swizzled V^T image to ws (linear copy, 1KB/wave stores).
  {
    ushort_t* dvp = wsV + ((size_t)u << 12);
    short8 a0 = *(const short8*)&vtS[tid * 16];
    short8 a1 = *(const short8*)&vtS[tid * 16 + 8];
    *(short8*)(dvp + tid * 16) = a0;
    *(short8*)(dvp + tid * 16 + 8) = a1;
  }

  ushort_t* dst = wsM + ((size_t)u << 12);
#pragma unroll
  for (int j = 0; j < 4; ++j) {
    f32x4 acc = {0.f, 0.f, 0.f, 0.f};
#pragma unroll
    for (int kk = 0; kk < 2; ++kk) {
      short8 kf = *(const short8*)&ktS[swz(16 * j + r16, kk * 32 + 8 * g)];
      acc = __builtin_amdgcn_mfma_f32_16x16x32_bf16(vf[kk], kf, acc, 0, 0, 0);
    }
#pragma unroll
    for (int reg = 0; reg < 4; ++reg)
      dst[(16 * w + 4 * g + reg) * 64 + 16 * j + r16] = (ushort_t)f2b(acc[reg]);
  }
}

// ---------------------------------------------------------------------------
// Kernel B: exclusive prefix over NC chunks per (b,h), packed bf16x2, fp32 accum.
// ---------------------------------------------------------------------------
__global__ __launch_bounds__(256) void kv_scan_kernel(uint_t* __restrict__ kvw) {
  const int gi = blockIdx.x * 256 + threadIdx.x;  // 65536 threads
  const int bh = gi >> 11, e = gi & 2047;
  uint_t* p = kvw + (size_t)bh * NC * 2048 + e;
  float r0 = 0.f, r1 = 0.f;
#pragma unroll
  for (int c = 0; c < NC; ++c) {
    uint_t xv = p[c * 2048];
    float lo = __uint_as_float(xv << 16);
    float hi = __uint_as_float(xv & 0xffff0000u);
    p[c * 2048] = ((uint_t)(ushort_t)f2b(r1) << 16) | (ushort_t)(ushort_t)f2b(r0);
    r0 += lo;
    r1 += hi;
  }
}

// ---------------------------------------------------------------------------
// Kernel C: O = gate * ( mask(Q K^T) V + Q M_prev ).  BARRIER-FREE:
// Q/K frags direct from fp32 qk; V^T/M frags direct from bf16 ws; scores
// bounce through a per-wave LDS region (intra-wave, lgkmcnt guard only).
// ---------------------------------------------------------------------------
__global__ __launch_bounds__(256) void attn_out_kernel(
    const float* __restrict__ qk, const float* __restrict__ nrm,
    const ushort_t* __restrict__ wsM, const ushort_t* __restrict__ wsV,
    float* __restrict__ out) {
  const int u = blockIdx.x;
  const int c = u & 31, h = (u >> 5) & 15, b = u >> 9;
  const int t0 = c * CHUNK;
  const int tid = threadIdx.x;
  const int w = tid >> 6, lane = tid & 63, g = lane >> 4, r16 = lane & 15;
  __shared__ short smS[4096];   // per-wave rows [16w,16w+16) only

  // Q fragments (rows 16w+r16), fp32 -> bf16 in-register.
  short8 qf[2];
#pragma unroll
  for (int kk = 0; kk < 2; ++kk) {
    const size_t t = (size_t)(b * Sq + t0 + 16 * w + r16);
    const float4* qp =
        (const float4*)(qk + ((t * 2 + 0) * Hq + h) * 64 + kk * 32 + 8 * g);
    float4 a = qp[0], bb = qp[1];
    short8 qv;
    qv[0] = f2b(a.x);  qv[1] = f2b(a.y);  qv[2] = f2b(a.z);  qv[3] = f2b(a.w);
    qv[4] = f2b(bb.x); qv[5] = f2b(bb.y); qv[6] = f2b(bb.z); qv[7] = f2b(bb.w);
    qf[kk] = qv;
  }

  // S = Q K^T for tiles j<=w; mask at the C/D lane map; bf16 into own LDS rows.
  for (int j = 0; j <= w; ++j) {
    f32x4 acc = {0.f, 0.f, 0.f, 0.f};
#pragma unroll
    for (int kk = 0; kk < 2; ++kk) {
      const size_t s = (size_t)(b * Sq + t0 + 16 * j + r16);
      const float4* kp =
          (const float4*)(qk + ((s * 2 + 1) * Hq + h) * 64 + kk * 32 + 8 * g);
      float4 a = kp[0], bb = kp[1];
      short8 kv_;
      kv_[0] = f2b(a.x);  kv_[1] = f2b(a.y);  kv_[2] = f2b(a.z);  kv_[3] = f2b(a.w);
      kv_[4] = f2b(bb.x); kv_[5] = f2b(bb.y); kv_[6] = f2b(bb.z); kv_[7] = f2b(bb.w);
      acc = __builtin_amdgcn_mfma_f32_16x16x32_bf16(qf[kk], kv_, acc, 0, 0, 0);
    }
    const int scol = 16 * j + r16;
#pragma unroll
    for (int reg = 0; reg < 4; ++reg) {
      const int trow = 16 * w + 4 * g + reg;
      smS[swz(trow, scol)] = (scol <= trow) ? f2b(acc[reg]) : (short)0;
    }
  }
  if (w == 0 || w == 2) {       // zero the one garbage tile the sf reads touch
    const int scol = 16 * (w + 1) + r16;
#pragma unroll
    for (int reg = 0; reg < 4; ++reg)
      smS[swz(16 * w + 4 * g + reg, scol)] = 0;
  }
  asm volatile("s_waitcnt lgkmcnt(0)" ::: "memory");   // intra-wave LDS drain
  __builtin_amdgcn_sched_barrier(0);

  const int nk = (w >> 1) + 1;  // live s-tiles per wave: 1,1,2,2
  short8 sf[2];
  for (int kk = 0; kk < nk; ++kk)
    sf[kk] = *(const short8*)&smS[swz(16 * w + r16, kk * 32 + 8 * g)];

  float gr[4];
#pragma unroll
  for (int reg = 0; reg < 4; ++reg)
    gr[reg] =
        __expf(-nrm[((size_t)(b * Sq) + t0 + 16 * w + 4 * g + reg) * Hq + h]);

  const ushort_t* vt = wsV + ((size_t)u << 12);
  const ushort_t* mm = wsM + ((size_t)u << 12);
#pragma unroll
  for (int j = 0; j < 4; ++j) {
    f32x4 acc = {0.f, 0.f, 0.f, 0.f};
    for (int kk = 0; kk < nk; ++kk) {
      short8 vfr = *(const short8*)(vt + swz(16 * j + r16, kk * 32 + 8 * g));
      acc = __builtin_amdgcn_mfma_f32_16x16x32_bf16(sf[kk], vfr, acc, 0, 0, 0);
    }
#pragma unroll
    for (int kk = 0; kk < 2; ++kk) {
      short8 mfr = *(const short8*)(mm + (16 * j + r16) * 64 + kk * 32 + 8 * g);
      acc = __builtin_amdgcn_mfma_f32_16x16x32_bf16(qf[kk], mfr, acc, 0, 0, 0);
    }
    const int dvv = 16 * j + r16;
#pragma unroll
    for (int reg = 0; reg < 4; ++reg) {
      const int trow = 16 * w + 4 * g + reg;
      out[((size_t)(b * Sq + t0 + trow) * Hq + h) * 64 + dvv] = gr[reg] * acc[reg];
    }
  }
}

extern "C" void kernel_launch(void* const* d_in, const int* in_sizes, int n_in,
                              void* d_out, int out_size, void* d_ws, size_t ws_size,
                              hipStream_t stream) {
  const float* qk = (const float*)d_in[0];
  const float* v  = (const float*)d_in[1];
  const float* nn = (const float*)d_in[2];
  float* out = (float*)d_out;
  ushort_t* wsM = (ushort_t*)d_ws;                     // 1024 tiles * 8KB
  ushort_t* wsV = wsM + ((size_t)1024 << 12);          // +8.39MB (total 16.78MB)

  kv_chunk_kernel<<<Bq * Hq * NC, 256, 0, stream>>>(qk, v, wsM, wsV);
  kv_scan_kernel<<<256, 256, 0, stream>>>((uint_t*)wsM);
  attn_out_kernel<<<Bq * Hq * NC, 256, 0, stream>>>(qk, nn, wsM, wsV, out);
}

// Round 6
// 34.713 us; speedup vs baseline: 1.5801x; 1.5801x over previous
//
#include <hip/hip_runtime.h>
#include <hip/hip_bf16.h>

#define Bq 2
#define Sq 2048
#define Hq 16
#define CHUNK 64
#define NC 32

typedef __attribute__((ext_vector_type(8))) short short8;  // 8 bf16
typedef __attribute__((ext_vector_type(4))) float f32x4;
typedef unsigned short ushort_t;
typedef unsigned int uint_t;

__device__ inline short f2b(float f) {
  __hip_bfloat16 h = __float2bfloat16(f);
  return *reinterpret_cast<short*>(&h);
}

// XOR-swizzled element index for a 64x64 bf16 tile (128B rows, 16B slots).
__device__ inline int swz(int row, int col) {
  return (row << 6) + ((((col >> 3) ^ (row & 7))) << 3) + (col & 7);
}

// ---------------------------------------------------------------------------
// Kernel A: per-chunk KV sums -> wsM (linear [dv][dk] bf16); V^T bf16 swizzled
// tile -> wsV.  (Identical to the round-4 version that passed.)
// ---------------------------------------------------------------------------
__global__ __launch_bounds__(256) void kv_chunk_kernel(
    const float* __restrict__ qk, const float* __restrict__ v,
    ushort_t* __restrict__ wsM, ushort_t* __restrict__ wsV) {
  const int u = blockIdx.x;
  const int c = u & 31, h = (u >> 5) & 15, b = u >> 9;
  const int t0 = c * CHUNK;
  const int tid = threadIdx.x;
  __shared__ short ktS[4096];   // K^T[dk][s], swizzled
  __shared__ short vtS[4096];   // V^T[dv][s], swizzled

  const int x = tid & 63, seg = tid >> 6;
  for (int e = 0; e < 2; ++e) {
    const int s0 = seg * 16 + e * 8;
    short8 kb, vb;
#pragma unroll
    for (int j = 0; j < 8; ++j) {
      const size_t t = (size_t)(b * Sq + t0 + s0 + j);
      kb[j] = f2b(qk[((t * 2 + 1) * Hq + h) * 64 + x]);   // coalesced column read
      vb[j] = f2b(v[(t * Hq + h) * 64 + x]);
    }
    *(short8*)&ktS[swz(x, s0)] = kb;
    *(short8*)&vtS[swz(x, s0)] = vb;
  }
  __syncthreads();

  const int w = tid >> 6, lane = tid & 63, g = lane >> 4, r16 = lane & 15;
  short8 vf[2];
#pragma unroll
  for (int kk = 0; kk < 2; ++kk)
    vf[kk] = *(const short8*)&vtS[swz(16 * w + r16, kk * 32 + 8 * g)];

  // Dump the swizzled V^T image to ws (linear 16B stores).
  {
    ushort_t* dvp = wsV + ((size_t)u << 12);
    short8 a0 = *(const short8*)&vtS[tid * 16];
    short8 a1 = *(const short8*)&vtS[tid * 16 + 8];
    *(short8*)(dvp + tid * 16) = a0;
    *(short8*)(dvp + tid * 16 + 8) = a1;
  }

  ushort_t* dst = wsM + ((size_t)u << 12);
#pragma unroll
  for (int j = 0; j < 4; ++j) {
    f32x4 acc = {0.f, 0.f, 0.f, 0.f};
#pragma unroll
    for (int kk = 0; kk < 2; ++kk) {
      short8 kf = *(const short8*)&ktS[swz(16 * j + r16, kk * 32 + 8 * g)];
      acc = __builtin_amdgcn_mfma_f32_16x16x32_bf16(vf[kk], kf, acc, 0, 0, 0);
    }
#pragma unroll
    for (int reg = 0; reg < 4; ++reg)
      dst[(16 * w + 4 * g + reg) * 64 + 16 * j + r16] = (ushort_t)f2b(acc[reg]);
  }
}

// ---------------------------------------------------------------------------
// Kernel B: exclusive prefix over NC chunks per (b,h).  All 32 loads issued
// up-front (independent), scan in registers, stores after.
// ---------------------------------------------------------------------------
__global__ __launch_bounds__(256) void kv_scan_kernel(uint_t* __restrict__ kvw) {
  const int gi = blockIdx.x * 256 + threadIdx.x;  // 65536 threads
  const int bh = gi >> 11, e = gi & 2047;
  uint_t* p = kvw + (size_t)bh * NC * 2048 + e;
  uint_t xv[NC];
#pragma unroll
  for (int c = 0; c < NC; ++c) xv[c] = p[c * 2048];
  float r0 = 0.f, r1 = 0.f;
#pragma unroll
  for (int c = 0; c < NC; ++c) {
    float lo = __uint_as_float(xv[c] << 16);
    float hi = __uint_as_float(xv[c] & 0xffff0000u);
    p[c * 2048] = ((uint_t)(ushort_t)f2b(r1) << 16) | (uint_t)(ushort_t)f2b(r0);
    r0 += lo;
    r1 += hi;
  }
}

// ---------------------------------------------------------------------------
// Kernel C: O = gate * ( mask(Q K^T) V + Q M_prev ).  ONE memory phase:
// all global loads (M, V^T, K fp32, Q fp32, n) issued before any compute,
// pinned by sched_barrier.  Unused fragments are zero-filled so the compute
// path is branchless (zeros through MFMA contribute nothing).
// ---------------------------------------------------------------------------
__global__ __launch_bounds__(256) void attn_out_kernel(
    const float* __restrict__ qk, const float* __restrict__ nrm,
    const ushort_t* __restrict__ wsM, const ushort_t* __restrict__ wsV,
    float* __restrict__ out) {
  const int u = blockIdx.x;
  const int c = u & 31, h = (u >> 5) & 15, b = u >> 9;
  const int t0 = c * CHUNK;
  const int tid = threadIdx.x;
  const int w = tid >> 6, lane = tid & 63, g = lane >> 4, r16 = lane & 15;
  __shared__ short smS[4096];   // per-wave rows [16w,16w+16)

  const ushort_t* mm = wsM + ((size_t)u << 12);
  const ushort_t* vt = wsV + ((size_t)u << 12);
  const int nk = (w >> 1) + 1;  // live s-tiles per wave: 1,1,2,2

  // ================= issue ALL global loads =================
  short8 mfr[4][2];
#pragma unroll
  for (int j = 0; j < 4; ++j)
#pragma unroll
    for (int kk = 0; kk < 2; ++kk)
      mfr[j][kk] = *(const short8*)(mm + (16 * j + r16) * 64 + kk * 32 + 8 * g);

  short8 vfr[4][2];
#pragma unroll
  for (int kk = 0; kk < 2; ++kk)
#pragma unroll
    for (int j = 0; j < 4; ++j) {
      if (kk < nk)
        vfr[j][kk] = *(const short8*)(vt + swz(16 * j + r16, kk * 32 + 8 * g));
      else
        vfr[j][kk] = short8{};
    }

  float4 kraw[4][4];   // K rows 16j+r16 (fp32, round-4-verified layout)
#pragma unroll
  for (int j = 0; j < 4; ++j) {
    const size_t s = (size_t)(b * Sq + t0 + 16 * j + r16);
    const float4* kp = (const float4*)(qk + ((s * 2 + 1) * Hq + h) * 64);
#pragma unroll
    for (int q = 0; q < 2; ++q) {
      if (j <= w) {
        kraw[j][2 * q]     = kp[8 * q + 2 * g];
        kraw[j][2 * q + 1] = kp[8 * q + 2 * g + 1];
      } else {
        kraw[j][2 * q]     = make_float4(0.f, 0.f, 0.f, 0.f);
        kraw[j][2 * q + 1] = make_float4(0.f, 0.f, 0.f, 0.f);
      }
    }
  }

  float4 qraw[4];
  {
    const size_t t = (size_t)(b * Sq + t0 + 16 * w + r16);
    const float4* qp = (const float4*)(qk + ((t * 2 + 0) * Hq + h) * 64);
#pragma unroll
    for (int q = 0; q < 2; ++q) {
      qraw[2 * q]     = qp[8 * q + 2 * g];
      qraw[2 * q + 1] = qp[8 * q + 2 * g + 1];
    }
  }

  float gn[4];
#pragma unroll
  for (int reg = 0; reg < 4; ++reg)
    gn[reg] = nrm[((size_t)(b * Sq) + t0 + 16 * w + 4 * g + reg) * Hq + h];

  __builtin_amdgcn_sched_barrier(0);   // pin all loads above all compute

  // ================= compute =================
  short8 qf[2];
#pragma unroll
  for (int kk = 0; kk < 2; ++kk) {
    float4 a = qraw[2 * kk], bb = qraw[2 * kk + 1];
    short8 qv;
    qv[0] = f2b(a.x);  qv[1] = f2b(a.y);  qv[2] = f2b(a.z);  qv[3] = f2b(a.w);
    qv[4] = f2b(bb.x); qv[5] = f2b(bb.y); qv[6] = f2b(bb.z); qv[7] = f2b(bb.w);
    qf[kk] = qv;
  }

  // S = Q K^T (all 4 tiles; j>w tiles are zeros), mask at the C/D lane map.
#pragma unroll
  for (int j = 0; j < 4; ++j) {
    f32x4 acc = {0.f, 0.f, 0.f, 0.f};
#pragma unroll
    for (int kk = 0; kk < 2; ++kk) {
      float4 a = kraw[j][2 * kk], bb = kraw[j][2 * kk + 1];
      short8 kf;
      kf[0] = f2b(a.x);  kf[1] = f2b(a.y);  kf[2] = f2b(a.z);  kf[3] = f2b(a.w);
      kf[4] = f2b(bb.x); kf[5] = f2b(bb.y); kf[6] = f2b(bb.z); kf[7] = f2b(bb.w);
      acc = __builtin_amdgcn_mfma_f32_16x16x32_bf16(qf[kk], kf, acc, 0, 0, 0);
    }
    const int scol = 16 * j + r16;
#pragma unroll
    for (int reg = 0; reg < 4; ++reg) {
      const int trow = 16 * w + 4 * g + reg;
      smS[swz(trow, scol)] = (scol <= trow) ? f2b(acc[reg]) : (short)0;
    }
  }
  asm volatile("s_waitcnt lgkmcnt(0)" ::: "memory");
  __builtin_amdgcn_sched_barrier(0);

  short8 sf0 = *(const short8*)&smS[swz(16 * w + r16, 8 * g)];
  short8 sf1 = short8{};
  if (nk > 1)
    sf1 = *(const short8*)&smS[swz(16 * w + r16, 32 + 8 * g)];

  float gr[4];
#pragma unroll
  for (int reg = 0; reg < 4; ++reg) gr[reg] = __expf(-gn[reg]);

#pragma unroll
  for (int j = 0; j < 4; ++j) {
    f32x4 acc = {0.f, 0.f, 0.f, 0.f};
    acc = __builtin_amdgcn_mfma_f32_16x16x32_bf16(sf0, vfr[j][0], acc, 0, 0, 0);
    acc = __builtin_amdgcn_mfma_f32_16x16x32_bf16(sf1, vfr[j][1], acc, 0, 0, 0);
    acc = __builtin_amdgcn_mfma_f32_16x16x32_bf16(qf[0], mfr[j][0], acc, 0, 0, 0);
    acc = __builtin_amdgcn_mfma_f32_16x16x32_bf16(qf[1], mfr[j][1], acc, 0, 0, 0);
    const int dvv = 16 * j + r16;
#pragma unroll
    for (int reg = 0; reg < 4; ++reg) {
      const int trow = 16 * w + 4 * g + reg;
      out[((size_t)(b * Sq + t0 + trow) * Hq + h) * 64 + dvv] = gr[reg] * acc[reg];
    }
  }
}

extern "C" void kernel_launch(void* const* d_in, const int* in_sizes, int n_in,
                              void* d_out, int out_size, void* d_ws, size_t ws_size,
                              hipStream_t stream) {
  const float* qk = (const float*)d_in[0];
  const float* v  = (const float*)d_in[1];
  const float* nn = (const float*)d_in[2];
  float* out = (float*)d_out;
  ushort_t* wsM = (ushort_t*)d_ws;                     // 1024 tiles * 8KB = 8.39MB
  ushort_t* wsV = wsM + ((size_t)1024 << 12);          // +8.39MB (total 16.78MB)

  kv_chunk_kernel<<<Bq * Hq * NC, 256, 0, stream>>>(qk, v, wsM, wsV);
  kv_scan_kernel<<<256, 256, 0, stream>>>((uint_t*)wsM);
  attn_out_kernel<<<Bq * Hq * NC, 256, 0, stream>>>(qk, nn, wsM, wsV, out);
}